// Round 1
// baseline (341.920 us; speedup 1.0000x reference)
//
#include <hip/hip_runtime.h>

#define NN   4096
#define EE   262144
#define ET   (EE + NN)
#define HH   4
#define EMB  256
#define DFF  128
#define FIN  128

typedef float  floatx4 __attribute__((ext_vector_type(4)));
typedef __bf16 bf16x8  __attribute__((ext_vector_type(8)));
typedef unsigned short u16;
typedef unsigned short u16x8 __attribute__((ext_vector_type(8)));

__device__ __forceinline__ u16 f2bf(float f) {
  unsigned u = __float_as_uint(f);
  u += 0x7fffu + ((u >> 16) & 1u);   // RNE
  return (u16)(u >> 16);
}

// ---------------- generic tiled fp32 GEMM:  C = act(A[M,K] * op(B) + bias) ----------------
// BT=true: B is [Nn,K] row-major (torch weight), use B^T.  BT=false: B is [K,Nn].
// omode 0: Cf[M][Nn] f32.  omode 1: Cb[(c>>6)*M + r][64 + (c&63)] bf16 (scaled).  omode 2: Cb[((c>>6)*64+(c&63))*M + r] bf16.
template <bool BT>
__global__ __launch_bounds__(256) void gemm_kernel(
    const float* __restrict__ A, const float* __restrict__ B,
    const float* __restrict__ bias, float* __restrict__ Cf, u16* __restrict__ Cb,
    int M, int Nn, int K, int act, int omode, float oscale)
{
  __shared__ float As[64][17];
  __shared__ float Bs[16][65];
  const int tid = threadIdx.x;
  const int tr = tid >> 4, tc = tid & 15;
  const int m0 = blockIdx.y * 64, n0 = blockIdx.x * 64;
  float acc[4][4] = {};
  for (int k0 = 0; k0 < K; k0 += 16) {
    {
      const int r = tid >> 2, kq = (tid & 3) << 2;
      const float4 av = *(const float4*)(A + (size_t)(m0 + r) * K + k0 + kq);
      As[r][kq] = av.x; As[r][kq + 1] = av.y; As[r][kq + 2] = av.z; As[r][kq + 3] = av.w;
    }
    if (!BT) {
      const int kk = tid >> 4, jq = (tid & 15) << 2;
      const float4 bv = *(const float4*)(B + (size_t)(k0 + kk) * Nn + n0 + jq);
      Bs[kk][jq] = bv.x; Bs[kk][jq + 1] = bv.y; Bs[kk][jq + 2] = bv.z; Bs[kk][jq + 3] = bv.w;
    } else {
      const int j = tid >> 2, kq = (tid & 3) << 2;
      const float4 bv = *(const float4*)(B + (size_t)(n0 + j) * K + k0 + kq);
      Bs[kq][j] = bv.x; Bs[kq + 1][j] = bv.y; Bs[kq + 2][j] = bv.z; Bs[kq + 3][j] = bv.w;
    }
    __syncthreads();
#pragma unroll
    for (int kk = 0; kk < 16; ++kk) {
      float a[4], b[4];
#pragma unroll
      for (int i = 0; i < 4; ++i) a[i] = As[tr * 4 + i][kk];
#pragma unroll
      for (int j = 0; j < 4; ++j) b[j] = Bs[kk][tc * 4 + j];
#pragma unroll
      for (int i = 0; i < 4; ++i)
#pragma unroll
        for (int j = 0; j < 4; ++j) acc[i][j] += a[i] * b[j];
    }
    __syncthreads();
  }
#pragma unroll
  for (int i = 0; i < 4; ++i) {
    const int r = m0 + tr * 4 + i;
#pragma unroll
    for (int j = 0; j < 4; ++j) {
      const int c = n0 + tc * 4 + j;
      float v = acc[i][j] + (bias ? bias[c] : 0.f);
      if (act == 1) v = v > 0.f ? v : 0.01f * v;
      else if (act == 2) v = v > 0.f ? v : 0.f;
      if (omode == 0) {
        Cf[(size_t)r * Nn + c] = v;
      } else {
        const u16 bw = f2bf(v * oscale);
        const int hh = c >> 6, dd = c & 63;
        if (omode == 1) Cb[((size_t)hh * M + r) * 64 + dd] = bw;
        else            Cb[((size_t)hh * 64 + dd) * M + r] = bw;
      }
    }
  }
}

// ---------------- a_s / a_d: per (node, head) attention pre-sums ----------------
__global__ __launch_bounds__(256) void att_sums(const float* __restrict__ xh,
                                                const float* __restrict__ att_src,
                                                const float* __restrict__ att_dst,
                                                float* __restrict__ a_s, float* __restrict__ a_d)
{
  const int n = blockIdx.x, t = threadIdx.x;
  const int h = t >> 6, c = t & 63;
  const float v = xh[(size_t)n * EMB + t];
  float s1 = v * att_src[t];
  float s2 = v * att_dst[t];
#pragma unroll
  for (int off = 32; off >= 1; off >>= 1) {
    s1 += __shfl_down(s1, off);
    s2 += __shfl_down(s2, off);
  }
  if (c == 0) { a_s[n * HH + h] = s1; a_d[n * HH + h] = s2; }
}

// ---------------- counting sort of edges by destination ----------------
__global__ void edge_count(const int* __restrict__ ei, int* __restrict__ counts) {
  const int e = blockIdx.x * blockDim.x + threadIdx.x;
  if (e >= ET) return;
  const int dst = (e < EE) ? ei[EE + e] : (e - EE);
  atomicAdd(&counts[dst], 1);
}

__global__ __launch_bounds__(64) void scan4096(const int* __restrict__ counts, int* __restrict__ offs) {
  const int t = threadIdx.x;          // 64 threads, 64 counts each
  const int base = t * 64;
  int s = 0;
  for (int i = 0; i < 64; ++i) s += counts[base + i];
  int incl = s;
#pragma unroll
  for (int off = 1; off < 64; off <<= 1) {
    const int v = __shfl_up(incl, off);
    if (t >= off) incl += v;
  }
  int run = incl - s;                 // exclusive prefix of this chunk
  for (int i = 0; i < 64; ++i) { offs[base + i] = run; run += counts[base + i]; }
}

__global__ void edge_scatter(const int* __restrict__ ei, const int* __restrict__ offs,
                             int* __restrict__ cursor, int* __restrict__ ssrc) {
  const int e = blockIdx.x * blockDim.x + threadIdx.x;
  if (e >= ET) return;
  int src, dst;
  if (e < EE) { src = ei[e]; dst = ei[EE + e]; } else { src = dst = e - EE; }
  const int pos = offs[dst] + atomicAdd(&cursor[dst], 1);
  ssrc[pos] = src;
}

// ---------------- GAT gather: edge softmax + weighted aggregation, no atomics ----------------
__global__ __launch_bounds__(256) void gat_gather(
    const float* __restrict__ xh, const float* __restrict__ a_s, const float* __restrict__ a_d,
    const int* __restrict__ offs, const int* __restrict__ counts, const int* __restrict__ ssrc,
    const float* __restrict__ b_gat, float* __restrict__ t_out)
{
  const int dst = blockIdx.x, tid = threadIdx.x;
  const int h = tid >> 6, c = tid & 63;
  const float ad = a_d[dst * HH + h];
  const int beg = offs[dst], deg = counts[dst];
  float accv = 0.f, den = 0.f;
  for (int i = 0; i < deg; ++i) {
    const int src = ssrc[beg + i];
    float a = a_s[src * HH + h] + ad;
    a = a > 0.f ? a : 0.2f * a;                 // leaky 0.2 on edge scores
    const float p = __expf(a);                  // no max-sub: |a| <~ 8, safe in fp32
    den += p;
    accv += p * xh[(size_t)src * EMB + h * 64 + c];
  }
  float v = accv / (den + 1e-16f) + b_gat[tid];
  v = v > 0.f ? v : 0.01f * v;                  // F.leaky_relu default slope
  t_out[(size_t)dst * EMB + tid] = v;
}

// ---------------- flash attention: 1 wave = 16 query rows, swapped-operand MFMA ----------------
__global__ __launch_bounds__(64) void flash_kernel(
    const u16* __restrict__ qb, const u16* __restrict__ kb,
    const u16* __restrict__ vT, float* __restrict__ o)
{
  const int h = blockIdx.y;
  const int q0 = blockIdx.x * 16;
  const int lane = threadIdx.x;
  const int lk = lane & 15, lg = lane >> 4;
  const u16* qh = qb + (size_t)h * NN * 64;
  const u16* kh = kb + (size_t)h * NN * 64;
  const u16* vh = vT + (size_t)h * 64 * NN;

  const bf16x8 qf0 = *(const bf16x8*)(qh + (size_t)(q0 + lk) * 64 + lg * 8);
  const bf16x8 qf1 = *(const bf16x8*)(qh + (size_t)(q0 + lk) * 64 + 32 + lg * 8);

  floatx4 ot[4];
  const floatx4 zf = {0.f, 0.f, 0.f, 0.f};
#pragma unroll
  for (int d = 0; d < 4; ++d) ot[d] = zf;
  float m_r = -1e30f, l_r = 0.f;

#pragma unroll 2
  for (int k0 = 0; k0 < NN; k0 += 32) {
    const u16* krow = kh + (size_t)(k0 + lk) * 64 + lg * 8;
    const bf16x8 kf00 = *(const bf16x8*)(krow);
    const bf16x8 kf01 = *(const bf16x8*)(krow + 32);
    const bf16x8 kf10 = *(const bf16x8*)(krow + 16 * 64);
    const bf16x8 kf11 = *(const bf16x8*)(krow + 16 * 64 + 32);
    // S^T[key][q] = K * Q^T  (D-layout: row=key=4*lg+i, col=q=lk)
    floatx4 sa = __builtin_amdgcn_mfma_f32_16x16x32_bf16(kf00, qf0, zf, 0, 0, 0);
    sa = __builtin_amdgcn_mfma_f32_16x16x32_bf16(kf01, qf1, sa, 0, 0, 0);
    floatx4 sb = __builtin_amdgcn_mfma_f32_16x16x32_bf16(kf10, qf0, zf, 0, 0, 0);
    sb = __builtin_amdgcn_mfma_f32_16x16x32_bf16(kf11, qf1, sb, 0, 0, 0);

    // online softmax over the 32 keys for this lane's q (=lk); groups hold disjoint keys
    float mx = fmaxf(fmaxf(fmaxf(sa[0], sa[1]), fmaxf(sa[2], sa[3])),
                     fmaxf(fmaxf(sb[0], sb[1]), fmaxf(sb[2], sb[3])));
    mx = fmaxf(mx, __shfl_xor(mx, 16));
    mx = fmaxf(mx, __shfl_xor(mx, 32));
    const float m_new = fmaxf(m_r, mx);
    const float corr = __expf(m_r - m_new);
    float pa[4], pb[4];
#pragma unroll
    for (int i = 0; i < 4; ++i) { pa[i] = __expf(sa[i] - m_new); pb[i] = __expf(sb[i] - m_new); }
    float sm = (pa[0] + pa[1]) + (pa[2] + pa[3]) + (pb[0] + pb[1]) + (pb[2] + pb[3]);
    sm += __shfl_xor(sm, 16);
    sm += __shfl_xor(sm, 32);
    l_r = l_r * corr + sm;
    m_r = m_new;
#pragma unroll
    for (int d = 0; d < 4; ++d) ot[d] *= corr;

    // redistribute P^T from D-layout (key=4*g'+i) to B-frag layout (key=8*lg+j), col q=lk kept
    union { u16x8 u; bf16x8 b; } cv;
#pragma unroll
    for (int j = 0; j < 8; ++j) {
      const int sg = ((lg & 1) << 1) | (j >> 2);
      const int sl = (sg << 4) | lk;
      const float va = __shfl(pa[j & 3], sl);
      const float vb = __shfl(pb[j & 3], sl);
      cv.u[j] = f2bf(lg < 2 ? va : vb);
    }
    const bf16x8 pf = cv.b;
    // o^T[d][q] += V^T[d][k] * P^T[k][q]
#pragma unroll
    for (int dt = 0; dt < 4; ++dt) {
      const bf16x8 vf = *(const bf16x8*)(vh + (size_t)(dt * 16 + lk) * NN + k0 + lg * 8);
      ot[dt] = __builtin_amdgcn_mfma_f32_16x16x32_bf16(vf, pf, ot[dt], 0, 0, 0);
    }
  }

  const float inv = 1.0f / l_r;
#pragma unroll
  for (int dt = 0; dt < 4; ++dt)
#pragma unroll
    for (int i = 0; i < 4; ++i)
      o[(size_t)(q0 + lk) * EMB + h * 64 + dt * 16 + lg * 4 + i] = ot[dt][i] * inv;
}

// ---------------- launch ----------------
extern "C" void kernel_launch(void* const* d_in, const int* in_sizes, int n_in,
                              void* d_out, int out_size, void* d_ws, size_t ws_size,
                              hipStream_t stream)
{
  const float* tgt   = (const float*)d_in[0];
  const float* mem   = (const float*)d_in[1];
  const float* orig  = (const float*)d_in[2];
  const int*   eidx  = (const int*)d_in[3];
  const float* Wg    = (const float*)d_in[4];
  const float* att_s = (const float*)d_in[5];
  const float* att_d = (const float*)d_in[6];
  const float* bg    = (const float*)d_in[7];
  const float* ipw   = (const float*)d_in[8];
  const float* ipb   = (const float*)d_in[9];
  const float* opw   = (const float*)d_in[10];
  const float* opb   = (const float*)d_in[11];
  const float* l1w   = (const float*)d_in[12];
  const float* l1b   = (const float*)d_in[13];
  float* out = (float*)d_out;

  char* ws = (char*)d_ws;
  size_t off = 0;
  auto alloc = [&](size_t bytes) -> void* {
    void* p = ws + off;
    off += (bytes + 255) & ~((size_t)255);
    return p;
  };
  float* xh    = (float*)alloc((size_t)NN * EMB * 4);
  float* tbuf  = (float*)alloc((size_t)NN * EMB * 4);
  float* obuf  = (float*)alloc((size_t)NN * EMB * 4);
  float* fused = (float*)alloc((size_t)NN * EMB * 4);
  float* a_s   = (float*)alloc((size_t)NN * HH * 4);
  float* a_d   = (float*)alloc((size_t)NN * HH * 4);
  int* counts  = (int*)alloc((size_t)NN * 4);
  int* offs    = (int*)alloc((size_t)NN * 4);
  int* cursor  = (int*)alloc((size_t)NN * 4);
  int* ssrc    = (int*)alloc((size_t)ET * 4);
  u16* qb      = (u16*)alloc((size_t)NN * EMB * 2);
  u16* kbuf    = (u16*)alloc((size_t)NN * EMB * 2);
  u16* vT      = (u16*)alloc((size_t)NN * EMB * 2);

  hipMemsetAsync(counts, 0, (size_t)NN * 4, stream);
  hipMemsetAsync(cursor, 0, (size_t)NN * 4, stream);

  // GAT linear: xh = tgt @ W_gat   (B is [K,N])
  gemm_kernel<false><<<dim3(EMB / 64, NN / 64), 256, 0, stream>>>(
      tgt, Wg, nullptr, xh, nullptr, NN, EMB, FIN, 0, 0, 1.f);
  att_sums<<<NN, 256, 0, stream>>>(xh, att_s, att_d, a_s, a_d);
  edge_count<<<(ET + 255) / 256, 256, 0, stream>>>(eidx, counts);
  scan4096<<<1, 64, 0, stream>>>(counts, offs);
  edge_scatter<<<(ET + 255) / 256, 256, 0, stream>>>(eidx, offs, cursor, ssrc);
  gat_gather<<<NN, 256, 0, stream>>>(xh, a_s, a_d, offs, counts, ssrc, bg, tbuf);

  // QKV projections (weights are [out,in] -> BT). q scaled by 1/sqrt(64)=0.125 into bf16.
  gemm_kernel<true><<<dim3(EMB / 64, NN / 64), 256, 0, stream>>>(
      tbuf, ipw, ipb, nullptr, qb, NN, EMB, EMB, 0, 1, 0.125f);
  gemm_kernel<true><<<dim3(EMB / 64, NN / 64), 256, 0, stream>>>(
      mem, ipw + EMB * EMB, ipb + EMB, nullptr, kbuf, NN, EMB, EMB, 0, 1, 1.f);
  gemm_kernel<true><<<dim3(EMB / 64, NN / 64), 256, 0, stream>>>(
      orig, ipw + 2 * EMB * EMB, ipb + 2 * EMB, nullptr, vT, NN, EMB, EMB, 0, 2, 1.f);

  flash_kernel<<<dim3(NN / 16, HH), 64, 0, stream>>>(qb, kbuf, vT, obuf);

  gemm_kernel<true><<<dim3(EMB / 64, NN / 64), 256, 0, stream>>>(
      obuf, opw, opb, fused, nullptr, NN, EMB, EMB, 0, 0, 1.f);
  gemm_kernel<true><<<dim3(DFF / 64, NN / 64), 256, 0, stream>>>(
      fused, l1w, l1b, out, nullptr, NN, DFF, EMB, 2, 0, 1.f);
}

// Round 2
// 325.982 us; speedup vs baseline: 1.0489x; 1.0489x over previous
//
#include <hip/hip_runtime.h>

#define NN   4096
#define EE   262144
#define ET   (EE + NN)
#define HH   4
#define EMB  256
#define DFF  128
#define FIN  128
#define KSPLIT 8
#define KCHUNK (NN / KSPLIT)

typedef float  floatx4 __attribute__((ext_vector_type(4)));
typedef __bf16 bf16x8  __attribute__((ext_vector_type(8)));
typedef unsigned short u16;
typedef unsigned short u16x8 __attribute__((ext_vector_type(8)));

__device__ __forceinline__ u16 f2bf(float f) {
  unsigned u = __float_as_uint(f);
  u += 0x7fffu + ((u >> 16) & 1u);   // RNE
  return (u16)(u >> 16);
}

// ---------------- generic tiled fp32 GEMM:  C = act(A[M,K] * op(B) + bias) ----------------
template <bool BT>
__global__ __launch_bounds__(256) void gemm_kernel(
    const float* __restrict__ A, const float* __restrict__ B,
    const float* __restrict__ bias, float* __restrict__ Cf, u16* __restrict__ Cb,
    int M, int Nn, int K, int act, int omode, float oscale)
{
  __shared__ float As[64][17];
  __shared__ float Bs[16][65];
  const int tid = threadIdx.x;
  const int tr = tid >> 4, tc = tid & 15;
  const int m0 = blockIdx.y * 64, n0 = blockIdx.x * 64;
  float acc[4][4] = {};
  for (int k0 = 0; k0 < K; k0 += 16) {
    {
      const int r = tid >> 2, kq = (tid & 3) << 2;
      const float4 av = *(const float4*)(A + (size_t)(m0 + r) * K + k0 + kq);
      As[r][kq] = av.x; As[r][kq + 1] = av.y; As[r][kq + 2] = av.z; As[r][kq + 3] = av.w;
    }
    if (!BT) {
      const int kk = tid >> 4, jq = (tid & 15) << 2;
      const float4 bv = *(const float4*)(B + (size_t)(k0 + kk) * Nn + n0 + jq);
      Bs[kk][jq] = bv.x; Bs[kk][jq + 1] = bv.y; Bs[kk][jq + 2] = bv.z; Bs[kk][jq + 3] = bv.w;
    } else {
      const int j = tid >> 2, kq = (tid & 3) << 2;
      const float4 bv = *(const float4*)(B + (size_t)(n0 + j) * K + k0 + kq);
      Bs[kq][j] = bv.x; Bs[kq + 1][j] = bv.y; Bs[kq + 2][j] = bv.z; Bs[kq + 3][j] = bv.w;
    }
    __syncthreads();
#pragma unroll
    for (int kk = 0; kk < 16; ++kk) {
      float a[4], b[4];
#pragma unroll
      for (int i = 0; i < 4; ++i) a[i] = As[tr * 4 + i][kk];
#pragma unroll
      for (int j = 0; j < 4; ++j) b[j] = Bs[kk][tc * 4 + j];
#pragma unroll
      for (int i = 0; i < 4; ++i)
#pragma unroll
        for (int j = 0; j < 4; ++j) acc[i][j] += a[i] * b[j];
    }
    __syncthreads();
  }
#pragma unroll
  for (int i = 0; i < 4; ++i) {
    const int r = m0 + tr * 4 + i;
#pragma unroll
    for (int j = 0; j < 4; ++j) {
      const int c = n0 + tc * 4 + j;
      float v = acc[i][j] + (bias ? bias[c] : 0.f);
      if (act == 1) v = v > 0.f ? v : 0.01f * v;
      else if (act == 2) v = v > 0.f ? v : 0.f;
      if (omode == 0) {
        Cf[(size_t)r * Nn + c] = v;
      } else {
        const u16 bw = f2bf(v * oscale);
        const int hh = c >> 6, dd = c & 63;
        if (omode == 1) Cb[((size_t)hh * M + r) * 64 + dd] = bw;
        else            Cb[((size_t)hh * 64 + dd) * M + r] = bw;
      }
    }
  }
}

// ---------------- fused QKV projection: blockIdx.z selects {Q,K,V} ----------------
__global__ __launch_bounds__(256) void qkv_kernel(
    const float* __restrict__ tbuf, const float* __restrict__ mem, const float* __restrict__ orig,
    const float* __restrict__ ipw, const float* __restrict__ ipb,
    u16* __restrict__ qb, u16* __restrict__ kbuf, u16* __restrict__ vT)
{
  __shared__ float As[64][17];
  __shared__ float Bs[16][65];
  const int z = blockIdx.z;
  const float* A = (z == 0) ? tbuf : (z == 1 ? mem : orig);
  const float* B = ipw + (size_t)z * EMB * EMB;
  const float* bias = ipb + z * EMB;
  const float oscale = (z == 0) ? 0.125f : 1.f;
  u16* Cb = (z == 0) ? qb : (z == 1 ? kbuf : vT);
  const int tid = threadIdx.x;
  const int tr = tid >> 4, tc = tid & 15;
  const int m0 = blockIdx.y * 64, n0 = blockIdx.x * 64;
  float acc[4][4] = {};
  for (int k0 = 0; k0 < EMB; k0 += 16) {
    {
      const int r = tid >> 2, kq = (tid & 3) << 2;
      const float4 av = *(const float4*)(A + (size_t)(m0 + r) * EMB + k0 + kq);
      As[r][kq] = av.x; As[r][kq + 1] = av.y; As[r][kq + 2] = av.z; As[r][kq + 3] = av.w;
    }
    {
      const int j = tid >> 2, kq = (tid & 3) << 2;
      const float4 bv = *(const float4*)(B + (size_t)(n0 + j) * EMB + k0 + kq);
      Bs[kq][j] = bv.x; Bs[kq + 1][j] = bv.y; Bs[kq + 2][j] = bv.z; Bs[kq + 3][j] = bv.w;
    }
    __syncthreads();
#pragma unroll
    for (int kk = 0; kk < 16; ++kk) {
      float a[4], b[4];
#pragma unroll
      for (int i = 0; i < 4; ++i) a[i] = As[tr * 4 + i][kk];
#pragma unroll
      for (int j = 0; j < 4; ++j) b[j] = Bs[kk][tc * 4 + j];
#pragma unroll
      for (int i = 0; i < 4; ++i)
#pragma unroll
        for (int j = 0; j < 4; ++j) acc[i][j] += a[i] * b[j];
    }
    __syncthreads();
  }
#pragma unroll
  for (int i = 0; i < 4; ++i) {
    const int r = m0 + tr * 4 + i;
#pragma unroll
    for (int j = 0; j < 4; ++j) {
      const int c = n0 + tc * 4 + j;
      const float v = acc[i][j] + bias[c];
      const u16 bw = f2bf(v * oscale);
      const int hh = c >> 6, dd = c & 63;
      if (z == 2) Cb[((size_t)hh * 64 + dd) * NN + r] = bw;   // V transposed
      else        Cb[((size_t)hh * NN + r) * 64 + dd] = bw;   // Q/K row-major per head
    }
  }
}

// ---------------- a_s / a_d: per (node, head) attention pre-sums ----------------
__global__ __launch_bounds__(256) void att_sums(const float* __restrict__ xh,
                                                const float* __restrict__ att_src,
                                                const float* __restrict__ att_dst,
                                                float* __restrict__ a_s, float* __restrict__ a_d)
{
  const int n = blockIdx.x, t = threadIdx.x;
  const int h = t >> 6, c = t & 63;
  const float v = xh[(size_t)n * EMB + t];
  float s1 = v * att_src[t];
  float s2 = v * att_dst[t];
#pragma unroll
  for (int off = 32; off >= 1; off >>= 1) {
    s1 += __shfl_down(s1, off);
    s2 += __shfl_down(s2, off);
  }
  if (c == 0) { a_s[n * HH + h] = s1; a_d[n * HH + h] = s2; }
}

// ---------------- counting sort of edges by destination ----------------
__global__ void edge_count(const int* __restrict__ ei, int* __restrict__ counts) {
  const int e = blockIdx.x * blockDim.x + threadIdx.x;
  if (e >= ET) return;
  const int dst = (e < EE) ? ei[EE + e] : (e - EE);
  atomicAdd(&counts[dst], 1);
}

__global__ __launch_bounds__(64) void scan4096(const int* __restrict__ counts, int* __restrict__ offs) {
  const int t = threadIdx.x;
  const int base = t * 64;
  int s = 0;
  for (int i = 0; i < 64; ++i) s += counts[base + i];
  int incl = s;
#pragma unroll
  for (int off = 1; off < 64; off <<= 1) {
    const int v = __shfl_up(incl, off);
    if (t >= off) incl += v;
  }
  int run = incl - s;
  for (int i = 0; i < 64; ++i) { offs[base + i] = run; run += counts[base + i]; }
}

__global__ void edge_scatter(const int* __restrict__ ei, const int* __restrict__ offs,
                             int* __restrict__ cursor, int* __restrict__ ssrc) {
  const int e = blockIdx.x * blockDim.x + threadIdx.x;
  if (e >= ET) return;
  int src, dst;
  if (e < EE) { src = ei[e]; dst = ei[EE + e]; } else { src = dst = e - EE; }
  const int pos = offs[dst] + atomicAdd(&cursor[dst], 1);
  ssrc[pos] = src;
}

// ---------------- GAT gather: edge softmax + weighted aggregation, no atomics ----------------
__global__ __launch_bounds__(256) void gat_gather(
    const float* __restrict__ xh, const float* __restrict__ a_s, const float* __restrict__ a_d,
    const int* __restrict__ offs, const int* __restrict__ counts, const int* __restrict__ ssrc,
    const float* __restrict__ b_gat, float* __restrict__ t_out)
{
  const int dst = blockIdx.x, tid = threadIdx.x;
  const int h = tid >> 6, c = tid & 63;
  const float ad = a_d[dst * HH + h];
  const int beg = offs[dst], deg = counts[dst];
  float accv = 0.f, den = 0.f;
  for (int i = 0; i < deg; ++i) {
    const int src = ssrc[beg + i];
    float a = a_s[src * HH + h] + ad;
    a = a > 0.f ? a : 0.2f * a;
    const float p = __expf(a);
    den += p;
    accv += p * xh[(size_t)src * EMB + h * 64 + c];
  }
  float v = accv / (den + 1e-16f) + b_gat[tid];
  v = v > 0.f ? v : 0.01f * v;
  t_out[(size_t)dst * EMB + tid] = v;
}

// ---------------- split-K flash attention: 4 waves/block, each wave one q-tile ----------------
__global__ __launch_bounds__(256) void flash_kernel(
    const u16* __restrict__ qb, const u16* __restrict__ kb,
    const u16* __restrict__ vT, float* __restrict__ po,
    float* __restrict__ pm, float* __restrict__ pl)
{
  const int h = blockIdx.y;
  const int bx = blockIdx.x;                 // (NN/64) * KSPLIT
  const int qs = bx / KSPLIT, ks = bx % KSPLIT;
  const int wid = threadIdx.x >> 6;
  const int lane = threadIdx.x & 63;
  const int q0 = qs * 64 + wid * 16;
  const int lk = lane & 15, lg = lane >> 4;
  const int kbeg = ks * KCHUNK;
  const u16* qh = qb + (size_t)h * NN * 64;
  const u16* kh = kb + (size_t)h * NN * 64;
  const u16* vh = vT + (size_t)h * 64 * NN;

  const bf16x8 qf0 = *(const bf16x8*)(qh + (size_t)(q0 + lk) * 64 + lg * 8);
  const bf16x8 qf1 = *(const bf16x8*)(qh + (size_t)(q0 + lk) * 64 + 32 + lg * 8);

  floatx4 ot[4];
  const floatx4 zf = {0.f, 0.f, 0.f, 0.f};
#pragma unroll
  for (int d = 0; d < 4; ++d) ot[d] = zf;
  float m_r = -1e30f, l_r = 0.f;

#pragma unroll 2
  for (int k0 = kbeg; k0 < kbeg + KCHUNK; k0 += 32) {
    const u16* krow = kh + (size_t)(k0 + lk) * 64 + lg * 8;
    const bf16x8 kf00 = *(const bf16x8*)(krow);
    const bf16x8 kf01 = *(const bf16x8*)(krow + 32);
    const bf16x8 kf10 = *(const bf16x8*)(krow + 16 * 64);
    const bf16x8 kf11 = *(const bf16x8*)(krow + 16 * 64 + 32);
    floatx4 sa = __builtin_amdgcn_mfma_f32_16x16x32_bf16(kf00, qf0, zf, 0, 0, 0);
    sa = __builtin_amdgcn_mfma_f32_16x16x32_bf16(kf01, qf1, sa, 0, 0, 0);
    floatx4 sb = __builtin_amdgcn_mfma_f32_16x16x32_bf16(kf10, qf0, zf, 0, 0, 0);
    sb = __builtin_amdgcn_mfma_f32_16x16x32_bf16(kf11, qf1, sb, 0, 0, 0);

    float mx = fmaxf(fmaxf(fmaxf(sa[0], sa[1]), fmaxf(sa[2], sa[3])),
                     fmaxf(fmaxf(sb[0], sb[1]), fmaxf(sb[2], sb[3])));
    mx = fmaxf(mx, __shfl_xor(mx, 16));
    mx = fmaxf(mx, __shfl_xor(mx, 32));
    const float m_new = fmaxf(m_r, mx);
    const float corr = __expf(m_r - m_new);
    float pa[4], pb[4];
#pragma unroll
    for (int i = 0; i < 4; ++i) { pa[i] = __expf(sa[i] - m_new); pb[i] = __expf(sb[i] - m_new); }
    float sm = (pa[0] + pa[1]) + (pa[2] + pa[3]) + (pb[0] + pb[1]) + (pb[2] + pb[3]);
    sm += __shfl_xor(sm, 16);
    sm += __shfl_xor(sm, 32);
    l_r = l_r * corr + sm;
    m_r = m_new;
#pragma unroll
    for (int d = 0; d < 4; ++d) ot[d] *= corr;

    union { u16x8 u; bf16x8 b; } cv;
#pragma unroll
    for (int j = 0; j < 8; ++j) {
      const int sg = ((lg & 1) << 1) | (j >> 2);
      const int sl = (sg << 4) | lk;
      const float va = __shfl(pa[j & 3], sl);
      const float vb = __shfl(pb[j & 3], sl);
      cv.u[j] = f2bf(lg < 2 ? va : vb);
    }
    const bf16x8 pf = cv.b;
#pragma unroll
    for (int dt = 0; dt < 4; ++dt) {
      const bf16x8 vf = *(const bf16x8*)(vh + (size_t)(dt * 16 + lk) * NN + k0 + lg * 8);
      ot[dt] = __builtin_amdgcn_mfma_f32_16x16x32_bf16(vf, pf, ot[dt], 0, 0, 0);
    }
  }

  // write partials (unnormalized o, plus m and l)
  const int pidx = (h * KSPLIT + ks) * NN + q0 + lk;
  float* pd = po + (size_t)pidx * 64;
#pragma unroll
  for (int dt = 0; dt < 4; ++dt)
#pragma unroll
    for (int i = 0; i < 4; ++i)
      pd[dt * 16 + lg * 4 + i] = ot[dt][i];
  if (lg == 0) { pm[pidx] = m_r; pl[pidx] = l_r; }
}

// ---------------- combine split-K partials ----------------
__global__ __launch_bounds__(256) void flash_combine(
    const float* __restrict__ po, const float* __restrict__ pm,
    const float* __restrict__ pl, float* __restrict__ o)
{
  const int q = blockIdx.x;
  const int t = threadIdx.x;
  const int h = t >> 6, d = t & 63;
  float mloc[KSPLIT];
  float M = -1e30f;
#pragma unroll
  for (int i = 0; i < KSPLIT; ++i) {
    mloc[i] = pm[(h * KSPLIT + i) * NN + q];
    M = fmaxf(M, mloc[i]);
  }
  float L = 0.f, acc = 0.f;
#pragma unroll
  for (int i = 0; i < KSPLIT; ++i) {
    const float w = __expf(mloc[i] - M);
    L += w * pl[(h * KSPLIT + i) * NN + q];
    acc += w * po[((size_t)(h * KSPLIT + i) * NN + q) * 64 + d];
  }
  o[(size_t)q * EMB + h * 64 + d] = acc / L;
}

// ---------------- launch ----------------
extern "C" void kernel_launch(void* const* d_in, const int* in_sizes, int n_in,
                              void* d_out, int out_size, void* d_ws, size_t ws_size,
                              hipStream_t stream)
{
  const float* tgt   = (const float*)d_in[0];
  const float* mem   = (const float*)d_in[1];
  const float* orig  = (const float*)d_in[2];
  const int*   eidx  = (const int*)d_in[3];
  const float* Wg    = (const float*)d_in[4];
  const float* att_s = (const float*)d_in[5];
  const float* att_d = (const float*)d_in[6];
  const float* bg    = (const float*)d_in[7];
  const float* ipw   = (const float*)d_in[8];
  const float* ipb   = (const float*)d_in[9];
  const float* opw   = (const float*)d_in[10];
  const float* opb   = (const float*)d_in[11];
  const float* l1w   = (const float*)d_in[12];
  const float* l1b   = (const float*)d_in[13];
  float* out = (float*)d_out;

  char* ws = (char*)d_ws;
  size_t off = 0;
  auto alloc = [&](size_t bytes) -> void* {
    void* p = ws + off;
    off += (bytes + 255) & ~((size_t)255);
    return p;
  };
  float* xh    = (float*)alloc((size_t)NN * EMB * 4);
  float* tbuf  = (float*)alloc((size_t)NN * EMB * 4);
  float* obuf  = (float*)alloc((size_t)NN * EMB * 4);
  float* fused = (float*)alloc((size_t)NN * EMB * 4);
  float* a_s   = (float*)alloc((size_t)NN * HH * 4);
  float* a_d   = (float*)alloc((size_t)NN * HH * 4);
  int* counts  = (int*)alloc((size_t)NN * 4);
  int* offs    = (int*)alloc((size_t)NN * 4);
  int* cursor  = (int*)alloc((size_t)NN * 4);
  int* ssrc    = (int*)alloc((size_t)ET * 4);
  u16* qb      = (u16*)alloc((size_t)NN * EMB * 2);
  u16* kbuf    = (u16*)alloc((size_t)NN * EMB * 2);
  u16* vT      = (u16*)alloc((size_t)NN * EMB * 2);
  float* po    = (float*)alloc((size_t)HH * KSPLIT * NN * 64 * 4);
  float* pm    = (float*)alloc((size_t)HH * KSPLIT * NN * 4);
  float* pl    = (float*)alloc((size_t)HH * KSPLIT * NN * 4);

  hipMemsetAsync(counts, 0, (size_t)NN * 4, stream);
  hipMemsetAsync(cursor, 0, (size_t)NN * 4, stream);

  // GAT linear: xh = tgt @ W_gat
  gemm_kernel<false><<<dim3(EMB / 64, NN / 64), 256, 0, stream>>>(
      tgt, Wg, nullptr, xh, nullptr, NN, EMB, FIN, 0, 0, 1.f);
  att_sums<<<NN, 256, 0, stream>>>(xh, att_s, att_d, a_s, a_d);
  edge_count<<<(ET + 255) / 256, 256, 0, stream>>>(eidx, counts);
  scan4096<<<1, 64, 0, stream>>>(counts, offs);
  edge_scatter<<<(ET + 255) / 256, 256, 0, stream>>>(eidx, offs, cursor, ssrc);
  gat_gather<<<NN, 256, 0, stream>>>(xh, a_s, a_d, offs, counts, ssrc, bg, tbuf);

  // fused QKV projection (z: 0=Q from tbuf, 1=K from memory, 2=V from original_signal)
  qkv_kernel<<<dim3(EMB / 64, NN / 64, 3), 256, 0, stream>>>(
      tbuf, mem, orig, ipw, ipb, qb, kbuf, vT);

  flash_kernel<<<dim3((NN / 64) * KSPLIT, HH), 256, 0, stream>>>(qb, kbuf, vT, po, pm, pl);
  flash_combine<<<NN, 256, 0, stream>>>(po, pm, pl, obuf);

  gemm_kernel<true><<<dim3(EMB / 64, NN / 64), 256, 0, stream>>>(
      obuf, opw, opb, fused, nullptr, NN, EMB, EMB, 0, 0, 1.f);
  gemm_kernel<true><<<dim3(DFF / 64, NN / 64), 256, 0, stream>>>(
      fused, l1w, l1b, out, nullptr, NN, DFF, EMB, 2, 0, 1.f);
}

// Round 7
// 302.885 us; speedup vs baseline: 1.1289x; 1.0763x over previous
//
#include <hip/hip_runtime.h>

#define NN   4096
#define EE   262144
#define ET   (EE + NN)
#define HH   4
#define EMB  256
#define DFF  128
#define FIN  128
#define KSPLIT 8
#define KCHUNK (NN / KSPLIT)

typedef float  f32x16  __attribute__((ext_vector_type(16)));
typedef __bf16 bf16x8  __attribute__((ext_vector_type(8)));
typedef unsigned short u16;
typedef unsigned short u16x4 __attribute__((ext_vector_type(4)));

__device__ __forceinline__ u16 f2bf(float f) {
  unsigned u = __float_as_uint(f);
  u += 0x7fffu + ((u >> 16) & 1u);   // RNE
  return (u16)(u >> 16);
}
// hi/lo bf16 split packed into one uint: lo16 = hi-part, hi16 = lo-part
__device__ __forceinline__ unsigned split1(float x) {
  const u16 h = f2bf(x);
  const float hf = __uint_as_float(((unsigned)h) << 16);
  const u16 l = f2bf(x - hf);
  return (unsigned)h | ((unsigned)l << 16);
}

// ---------------- fp32 tiled GEMM (xh = tgt @ W_gat; feeds exponentials) ----------------
__global__ __launch_bounds__(256) void gemm_f32(
    const float* __restrict__ A, const float* __restrict__ B,
    float* __restrict__ Cf, int M, int Nn, int K)
{
  __shared__ float As[64][17];
  __shared__ float Bs[16][65];
  const int tid = threadIdx.x;
  const int tr = tid >> 4, tc = tid & 15;
  const int m0 = blockIdx.y * 64, n0 = blockIdx.x * 64;
  float acc[4][4] = {};
  for (int k0 = 0; k0 < K; k0 += 16) {
    {
      const int r = tid >> 2, kq = (tid & 3) << 2;
      const float4 av = *(const float4*)(A + (size_t)(m0 + r) * K + k0 + kq);
      As[r][kq] = av.x; As[r][kq + 1] = av.y; As[r][kq + 2] = av.z; As[r][kq + 3] = av.w;
    }
    {
      const int kk = tid >> 4, jq = (tid & 15) << 2;
      const float4 bv = *(const float4*)(B + (size_t)(k0 + kk) * Nn + n0 + jq);
      Bs[kk][jq] = bv.x; Bs[kk][jq + 1] = bv.y; Bs[kk][jq + 2] = bv.z; Bs[kk][jq + 3] = bv.w;
    }
    __syncthreads();
#pragma unroll
    for (int kk = 0; kk < 16; ++kk) {
      float a[4], b[4];
#pragma unroll
      for (int i = 0; i < 4; ++i) a[i] = As[tr * 4 + i][kk];
#pragma unroll
      for (int j = 0; j < 4; ++j) b[j] = Bs[kk][tc * 4 + j];
#pragma unroll
      for (int i = 0; i < 4; ++i)
#pragma unroll
        for (int j = 0; j < 4; ++j) acc[i][j] += a[i] * b[j];
    }
    __syncthreads();
  }
#pragma unroll
  for (int i = 0; i < 4; ++i)
#pragma unroll
    for (int j = 0; j < 4; ++j)
      Cf[(size_t)(m0 + tr * 4 + i) * Nn + n0 + tc * 4 + j] = acc[i][j];
}

// ------- split-precision MFMA GEMM: C = act(A[M,K] @ B[Nn,K]^T + bias), ~fp32 accurate -------
__global__ __launch_bounds__(256) void mgemm(
    const float* __restrict__ A, const float* __restrict__ B, const float* __restrict__ bias,
    float* __restrict__ Cf, u16* __restrict__ Cb,
    int M, int Nn, int K, int act, int omode, float oscale)
{
  __shared__ u16 Ah[64][40], Al[64][40], Bh[64][40], Bl[64][40];
  const int tid = threadIdx.x;
  const int m0 = blockIdx.y * 64, n0 = blockIdx.x * 64;
  const int w = tid >> 6, l = tid & 63, lq = l & 31, hi = l >> 5;
  const int wm = w >> 1, wn = w & 1;
  f32x16 acc = {0};
  for (int k0 = 0; k0 < K; k0 += 32) {
    __syncthreads();
#pragma unroll
    for (int it = 0; it < 2; ++it) {
      const int idx = tid + it * 256;
      const int row = idx >> 3, slot = idx & 7;
      const float4 av = *(const float4*)(A + (size_t)(m0 + row) * K + k0 + slot * 4);
      const unsigned sa0 = split1(av.x), sa1 = split1(av.y), sa2 = split1(av.z), sa3 = split1(av.w);
      u16x4 ahp = {(u16)sa0, (u16)sa1, (u16)sa2, (u16)sa3};
      u16x4 alp = {(u16)(sa0 >> 16), (u16)(sa1 >> 16), (u16)(sa2 >> 16), (u16)(sa3 >> 16)};
      *(u16x4*)(&Ah[row][slot * 4]) = ahp;
      *(u16x4*)(&Al[row][slot * 4]) = alp;
      const float4 bv = *(const float4*)(B + (size_t)(n0 + row) * K + k0 + slot * 4);
      const unsigned sb0 = split1(bv.x), sb1 = split1(bv.y), sb2 = split1(bv.z), sb3 = split1(bv.w);
      u16x4 bhp = {(u16)sb0, (u16)sb1, (u16)sb2, (u16)sb3};
      u16x4 blp = {(u16)(sb0 >> 16), (u16)(sb1 >> 16), (u16)(sb2 >> 16), (u16)(sb3 >> 16)};
      *(u16x4*)(&Bh[row][slot * 4]) = bhp;
      *(u16x4*)(&Bl[row][slot * 4]) = blp;
    }
    __syncthreads();
#pragma unroll
    for (int c = 0; c < 2; ++c) {
      const bf16x8 ah = *(const bf16x8*)(&Ah[wm * 32 + lq][c * 16 + hi * 8]);
      const bf16x8 al = *(const bf16x8*)(&Al[wm * 32 + lq][c * 16 + hi * 8]);
      const bf16x8 bh = *(const bf16x8*)(&Bh[wn * 32 + lq][c * 16 + hi * 8]);
      const bf16x8 bl = *(const bf16x8*)(&Bl[wn * 32 + lq][c * 16 + hi * 8]);
      acc = __builtin_amdgcn_mfma_f32_32x32x16_bf16(ah, bh, acc, 0, 0, 0);
      acc = __builtin_amdgcn_mfma_f32_32x32x16_bf16(ah, bl, acc, 0, 0, 0);
      acc = __builtin_amdgcn_mfma_f32_32x32x16_bf16(al, bh, acc, 0, 0, 0);
    }
  }
  const int col = n0 + wn * 32 + lq;
  const float bcol = bias ? bias[col] : 0.f;
#pragma unroll
  for (int r = 0; r < 16; ++r) {
    const int row = m0 + wm * 32 + (r & 3) + 8 * (r >> 2) + 4 * hi;
    float v = acc[r] + bcol;
    if (act == 1) v = v > 0.f ? v : 0.01f * v;
    else if (act == 2) v = fmaxf(v, 0.f);
    if (omode == 0) {
      Cf[(size_t)row * Nn + col] = v;
    } else {
      const u16 bw = f2bf(v * oscale);
      const int hh = col >> 6, dd = col & 63;
      if (omode == 1) Cb[((size_t)hh * M + row) * 64 + dd] = bw;
      else            Cb[((size_t)hh * 64 + dd) * M + row] = bw;
    }
  }
}

// ---------------- a_s / a_d per (node, head) ----------------
__global__ __launch_bounds__(256) void att_sums(const float* __restrict__ xh,
                                                const float* __restrict__ att_src,
                                                const float* __restrict__ att_dst,
                                                float* __restrict__ a_s, float* __restrict__ a_d)
{
  const int n = blockIdx.x, t = threadIdx.x;
  const int h = t >> 6, c = t & 63;
  const float v = xh[(size_t)n * EMB + t];
  float s1 = v * att_src[t];
  float s2 = v * att_dst[t];
#pragma unroll
  for (int off = 32; off >= 1; off >>= 1) {
    s1 += __shfl_down(s1, off);
    s2 += __shfl_down(s2, off);
  }
  if (c == 0) { a_s[n * HH + h] = s1; a_d[n * HH + h] = s2; }
}

// ---------------- counting sort of edges by destination ----------------
__global__ void edge_count(const int* __restrict__ ei, int* __restrict__ counts) {
  const int e = blockIdx.x * blockDim.x + threadIdx.x;
  if (e >= ET) return;
  const int dst = (e < EE) ? ei[EE + e] : (e - EE);
  atomicAdd(&counts[dst], 1);
}

__global__ __launch_bounds__(64) void scan4096(const int* __restrict__ counts, int* __restrict__ offs) {
  const int t = threadIdx.x;
  const int base = t * 64;
  int s = 0;
  for (int i = 0; i < 64; ++i) s += counts[base + i];
  int incl = s;
#pragma unroll
  for (int off = 1; off < 64; off <<= 1) {
    const int v = __shfl_up(incl, off);
    if (t >= off) incl += v;
  }
  int run = incl - s;
  for (int i = 0; i < 64; ++i) { offs[base + i] = run; run += counts[base + i]; }
}

__global__ void edge_scatter(const int* __restrict__ ei, const int* __restrict__ offs,
                             int* __restrict__ cursor, int* __restrict__ ssrc) {
  const int e = blockIdx.x * blockDim.x + threadIdx.x;
  if (e >= ET) return;
  int src, dst;
  if (e < EE) { src = ei[e]; dst = ei[EE + e]; } else { src = dst = e - EE; }
  const int pos = offs[dst] + atomicAdd(&cursor[dst], 1);
  ssrc[pos] = src;
}

// ---------------- GAT gather ----------------
__global__ __launch_bounds__(256) void gat_gather(
    const float* __restrict__ xh, const float* __restrict__ a_s, const float* __restrict__ a_d,
    const int* __restrict__ offs, const int* __restrict__ counts, const int* __restrict__ ssrc,
    const float* __restrict__ b_gat, float* __restrict__ t_out)
{
  const int dst = blockIdx.x, tid = threadIdx.x;
  const int h = tid >> 6, c = tid & 63;
  const float ad = a_d[dst * HH + h];
  const int beg = offs[dst], deg = counts[dst];
  float accv = 0.f, den = 0.f;
  for (int i = 0; i < deg; ++i) {
    const int src = ssrc[beg + i];
    float a = a_s[src * HH + h] + ad;
    a = a > 0.f ? a : 0.2f * a;
    const float p = __expf(a);
    den += p;
    accv += p * xh[(size_t)src * EMB + h * 64 + c];
  }
  float v = accv / (den + 1e-16f) + b_gat[tid];
  v = v > 0.f ? v : 0.01f * v;
  t_out[(size_t)dst * EMB + tid] = v;
}

// ---------------- flash attention: 32x32 swapped-operand; verified-primitive P path ----------------
// P redistribution to FLAT layout (pf0 elem j <-> key 8*hi+j) matching flat-loaded V:
// pairing-correct for any shared A/B fragment microlayout (same invariance that made R1 pass).
__global__ __launch_bounds__(256) void flash32(
    const u16* __restrict__ qb, const u16* __restrict__ kb,
    const u16* __restrict__ vT, float* __restrict__ po,
    float* __restrict__ pm, float* __restrict__ pl)
{
  const int h = blockIdx.y;
  const int qgroup = blockIdx.x / KSPLIT, ks = blockIdx.x % KSPLIT;
  const int w = threadIdx.x >> 6, l = threadIdx.x & 63;
  const int lq = l & 31, hi = l >> 5;
  const int qtile = qgroup * 4 + w;            // 4 waves share the K/V stream (L1 reuse)
  const int q0 = qtile * 32;
  const u16* qh = qb + (size_t)h * NN * 64;
  const u16* kh = kb + (size_t)h * NN * 64;
  const u16* vh = vT + (size_t)h * 64 * NN;

  bf16x8 qf[4];
#pragma unroll
  for (int c = 0; c < 4; ++c)
    qf[c] = *(const bf16x8*)(qh + (size_t)(q0 + lq) * 64 + c * 16 + hi * 8);

  f32x16 o0 = {0}, o1 = {0};
  float m_r = -1e30f, l_r = 0.f;

  const int kend = ks * KCHUNK + KCHUNK;
  for (int k0 = ks * KCHUNK; k0 < kend; k0 += 32) {
    f32x16 s = {0};
#pragma unroll
    for (int c = 0; c < 4; ++c) {
      const bf16x8 kf = *(const bf16x8*)(kh + (size_t)(k0 + lq) * 64 + c * 16 + hi * 8);
      s = __builtin_amdgcn_mfma_f32_32x32x16_bf16(kf, qf[c], s, 0, 0, 0);
    }
    // in-lane 16-key max, then cross-half reduce via verified shfl_xor(32)
    float mx = s[0];
#pragma unroll
    for (int i = 1; i < 16; ++i) mx = fmaxf(mx, s[i]);
    const float colmax = fmaxf(mx, __shfl_xor(mx, 32));
    if (!__all(colmax <= m_r + 8.f)) {          // defer-max (T13)
      const float m_new = fmaxf(m_r, colmax);
      const float corr = __expf(m_r - m_new);
#pragma unroll
      for (int i = 0; i < 16; ++i) { o0[i] *= corr; o1[i] *= corr; }
      l_r *= corr;
      m_r = m_new;
    }
    float p[16];
    float ssum = 0.f;
#pragma unroll
    for (int i = 0; i < 16; ++i) { p[i] = __expf(s[i] - m_r); ssum += p[i]; }
    l_r += ssum + __shfl_xor(ssum, 32);

    // pack P (scalar f2bf, verified) : word wi = keys (kk(2i,hi), kk(2i+1,hi)), kk(r,hi)=(r&3)+8*(r>>2)+4*hi
    unsigned wd[8];
#pragma unroll
    for (int i = 0; i < 8; ++i)
      wd[i] = (unsigned)f2bf(p[2 * i]) | ((unsigned)f2bf(p[2 * i + 1]) << 16);
    // redistribute to FLAT: one shfl_xor(32) per word-pair
    const unsigned t0 = __shfl_xor(hi ? wd[0] : wd[2], 32);
    const unsigned t1 = __shfl_xor(hi ? wd[1] : wd[3], 32);
    const unsigned t2 = __shfl_xor(hi ? wd[4] : wd[6], 32);
    const unsigned t3 = __shfl_xor(hi ? wd[5] : wd[7], 32);
    union { unsigned u[4]; bf16x8 b; } pf0, pf1;
    pf0.u[0] = hi ? t0 : wd[0];   // keys (8hi+0, 8hi+1)
    pf0.u[1] = hi ? t1 : wd[1];   // keys (8hi+2, 8hi+3)
    pf0.u[2] = hi ? wd[2] : t0;   // keys (8hi+4, 8hi+5)
    pf0.u[3] = hi ? wd[3] : t1;   // keys (8hi+6, 8hi+7)
    pf1.u[0] = hi ? t2 : wd[4];
    pf1.u[1] = hi ? t3 : wd[5];
    pf1.u[2] = hi ? wd[6] : t2;
    pf1.u[3] = hi ? wd[7] : t3;
    {
      const u16* vrow = vh + (size_t)lq * NN + k0 + hi * 8;
      const bf16x8 vf0 = *(const bf16x8*)(vrow);         // V^T[lq][k0+8hi+j]   (flat)
      const bf16x8 vf1 = *(const bf16x8*)(vrow + 16);
      o0 = __builtin_amdgcn_mfma_f32_32x32x16_bf16(vf0, pf0.b, o0, 0, 0, 0);
      o0 = __builtin_amdgcn_mfma_f32_32x32x16_bf16(vf1, pf1.b, o0, 0, 0, 0);
    }
    {
      const u16* vrow = vh + (size_t)(32 + lq) * NN + k0 + hi * 8;
      const bf16x8 vf0 = *(const bf16x8*)(vrow);
      const bf16x8 vf1 = *(const bf16x8*)(vrow + 16);
      o1 = __builtin_amdgcn_mfma_f32_32x32x16_bf16(vf0, pf0.b, o1, 0, 0, 0);
      o1 = __builtin_amdgcn_mfma_f32_32x32x16_bf16(vf1, pf1.b, o1, 0, 0, 0);
    }
  }

  const size_t base = ((size_t)(h * KSPLIT + ks) * 128 + qtile) * 2048;
#pragma unroll
  for (int r = 0; r < 16; ++r) {
    po[base + (size_t)((r * 2 + hi) * 32) + lq] = o0[r];
    po[base + (size_t)(((16 + r) * 2 + hi) * 32) + lq] = o1[r];
  }
  if (hi == 0) {
    const int pidx = (h * KSPLIT + ks) * NN + q0 + lq;
    pm[pidx] = m_r; pl[pidx] = l_r;
  }
}

// ---------------- combine split-K partials ----------------
__global__ __launch_bounds__(256) void combine2(
    const float* __restrict__ po, const float* __restrict__ pm,
    const float* __restrict__ pl, float* __restrict__ o)
{
  const int q = blockIdx.x;
  const int t = threadIdx.x;
  const int h = t >> 6, d = t & 63;
  const int qtile = q >> 5, qq = q & 31;
  const int dtile = d >> 5, dd = d & 31;
  const int dhi = (dd >> 2) & 1;
  const int r = (dd & 3) | (((dd >> 3) & 3) << 2);
  const int slot = (dtile * 16 + r) * 2 + dhi;
  float mloc[KSPLIT];
  float M = -1e30f;
#pragma unroll
  for (int i = 0; i < KSPLIT; ++i) {
    mloc[i] = pm[(h * KSPLIT + i) * NN + q];
    M = fmaxf(M, mloc[i]);
  }
  float L = 0.f, acc = 0.f;
#pragma unroll
  for (int i = 0; i < KSPLIT; ++i) {
    const float wgt = __expf(mloc[i] - M);
    L += wgt * pl[(h * KSPLIT + i) * NN + q];
    acc += wgt * po[((size_t)(h * KSPLIT + i) * 128 + qtile) * 2048 + slot * 32 + qq];
  }
  o[(size_t)q * EMB + h * 64 + d] = acc / L;
}

// ---------------- launch ----------------
extern "C" void kernel_launch(void* const* d_in, const int* in_sizes, int n_in,
                              void* d_out, int out_size, void* d_ws, size_t ws_size,
                              hipStream_t stream)
{
  const float* tgt   = (const float*)d_in[0];
  const float* mem   = (const float*)d_in[1];
  const float* orig  = (const float*)d_in[2];
  const int*   eidx  = (const int*)d_in[3];
  const float* Wg    = (const float*)d_in[4];
  const float* att_s = (const float*)d_in[5];
  const float* att_d = (const float*)d_in[6];
  const float* bg    = (const float*)d_in[7];
  const float* ipw   = (const float*)d_in[8];
  const float* ipb   = (const float*)d_in[9];
  const float* opw   = (const float*)d_in[10];
  const float* opb   = (const float*)d_in[11];
  const float* l1w   = (const float*)d_in[12];
  const float* l1b   = (const float*)d_in[13];
  float* out = (float*)d_out;

  char* ws = (char*)d_ws;
  size_t off = 0;
  auto alloc = [&](size_t bytes) -> void* {
    void* p = ws + off;
    off += (bytes + 255) & ~((size_t)255);
    return p;
  };
  float* xh    = (float*)alloc((size_t)NN * EMB * 4);
  float* tbuf  = (float*)alloc((size_t)NN * EMB * 4);
  float* obuf  = (float*)alloc((size_t)NN * EMB * 4);
  float* fused = (float*)alloc((size_t)NN * EMB * 4);
  float* a_s   = (float*)alloc((size_t)NN * HH * 4);
  float* a_d   = (float*)alloc((size_t)NN * HH * 4);
  int* counts  = (int*)alloc((size_t)NN * 4);
  int* offs    = (int*)alloc((size_t)NN * 4);
  int* cursor  = (int*)alloc((size_t)NN * 4);
  int* ssrc    = (int*)alloc((size_t)ET * 4);
  u16* qb      = (u16*)alloc((size_t)NN * EMB * 2);
  u16* kbuf    = (u16*)alloc((size_t)NN * EMB * 2);
  u16* vT      = (u16*)alloc((size_t)NN * EMB * 2);
  float* po    = (float*)alloc((size_t)HH * KSPLIT * NN * 64 * 4);
  float* pm    = (float*)alloc((size_t)HH * KSPLIT * NN * 4);
  float* pl    = (float*)alloc((size_t)HH * KSPLIT * NN * 4);

  (void)hipMemsetAsync(counts, 0, (size_t)NN * 4, stream);
  (void)hipMemsetAsync(cursor, 0, (size_t)NN * 4, stream);

  gemm_f32<<<dim3(EMB / 64, NN / 64), 256, 0, stream>>>(tgt, Wg, xh, NN, EMB, FIN);
  att_sums<<<NN, 256, 0, stream>>>(xh, att_s, att_d, a_s, a_d);
  edge_count<<<(ET + 255) / 256, 256, 0, stream>>>(eidx, counts);
  scan4096<<<1, 64, 0, stream>>>(counts, offs);
  edge_scatter<<<(ET + 255) / 256, 256, 0, stream>>>(eidx, offs, cursor, ssrc);
  gat_gather<<<NN, 256, 0, stream>>>(xh, a_s, a_d, offs, counts, ssrc, bg, tbuf);

  mgemm<<<dim3(EMB / 64, NN / 64), 256, 0, stream>>>(
      tbuf, ipw, ipb, nullptr, qb, NN, EMB, EMB, 0, 1, 0.125f);
  mgemm<<<dim3(EMB / 64, NN / 64), 256, 0, stream>>>(
      mem, ipw + EMB * EMB, ipb + EMB, nullptr, kbuf, NN, EMB, EMB, 0, 1, 1.f);
  mgemm<<<dim3(EMB / 64, NN / 64), 256, 0, stream>>>(
      orig, ipw + 2 * EMB * EMB, ipb + 2 * EMB, nullptr, vT, NN, EMB, EMB, 0, 2, 1.f);

  flash32<<<dim3(32 * KSPLIT, HH), 256, 0, stream>>>(qb, kbuf, vT, po, pm, pl);
  combine2<<<NN, 256, 0, stream>>>(po, pm, pl, obuf);

  mgemm<<<dim3(EMB / 64, NN / 64), 256, 0, stream>>>(
      obuf, opw, opb, fused, nullptr, NN, EMB, EMB, 0, 0, 1.f);
  mgemm<<<dim3(DFF / 64, NN / 64), 256, 0, stream>>>(
      fused, l1w, l1b, out, nullptr, NN, DFF, EMB, 2, 0, 1.f);
}